// Round 7
// baseline (362.134 us; speedup 1.0000x reference)
//
#include <hip/hip_runtime.h>
#include <stdint.h>

typedef unsigned long long u64;
typedef __attribute__((ext_vector_type(8))) short short8;   // 8 bf16 (4 VGPRs)
typedef __attribute__((ext_vector_type(4))) float f32x4;

#define KROWS  262144
#define DDIM   64
#define NQ     1024
#define NC     256                // K-chunks
#define CHUNK  (KROWS / NC)       // 1024 rows
#define SUB    128                // rows per LDS subtile
#define NSUB   (CHUNK / SUB)      // 8
#define KC_PER 4                  // u32 keys kept per (chunk,query) = one uint4
#define BIAS   128.0f             // acc bias => sims positive => raw bits monotone
#define SIMMASK 0xFFFFFC00u       // top 22 bits sim, low 10 bits row-in-chunk

__device__ __forceinline__ uint32_t ord32(float f) {
    uint32_t u = __float_as_uint(f);
    return (u & 0x80000000u) ? ~u : (u | 0x80000000u);
}
__device__ __forceinline__ uint32_t maxu(uint32_t a, uint32_t b) { return a > b ? a : b; }
__device__ __forceinline__ uint32_t minu(uint32_t a, uint32_t b) { return a < b ? a : b; }
// sorted-desc pair fold: 3 VALU
__device__ __forceinline__ void fold2(uint32_t& t0, uint32_t& t1, uint32_t k) {
    t1 = maxu(t1, minu(t0, k));
    t0 = maxu(t0, k);
}
// sorted-desc 4-list fold: 7 VALU
__device__ __forceinline__ void fold4(uint32_t (&t)[4], uint32_t k) {
    uint32_t n1 = maxu(t[1], minu(t[0], k));
    uint32_t n2 = maxu(t[2], minu(t[1], k));
    uint32_t n3 = maxu(t[3], minu(t[2], k));
    t[0] = maxu(t[0], k);
    t[1] = n1; t[2] = n2; t[3] = n3;
}
__device__ __forceinline__ uint32_t bf16rne(float f) {
    uint32_t u = __float_as_uint(f);
    return (u + 0x7fffu + ((u >> 16) & 1u)) >> 16;
}
__device__ __forceinline__ uint32_t pack2(float a, float b) {
    return bf16rne(a) | (bf16rne(b) << 16);
}

// Kernel 1: bf16 MFMA prefilter with FUSED fp32->bf16 staging (no conv
// kernel): threads load fp32 rows coalesced, convert (same RNE as before —
// selection bit-identical), ds_write into swizzled dbuf LDS. Per-class top-2
// fold, u32 keys (sim22 | row10). Block = 512 thr, grid (4 qcols, 256 chunks).
__global__ __launch_bounds__(512, 4) void p1(const float* __restrict__ Qg,
                                             const float* __restrict__ Mf,
                                             uint32_t* __restrict__ wsK) {
    __shared__ __align__(16) uint16_t stage[2 * 8192];   // 2 x 16 KiB dbuf
    const int t = threadIdx.x;
    const int lane = t & 63;
    const int w = t >> 6;
    const int quad = lane >> 4;
    const int m = lane & 15;
    const int qcol = blockIdx.x;
    const int chunk = blockIdx.y;
    const int qBase = qcol * 256 + w * 32;
    const int rowChunk = chunk * CHUNK;

    // A-frags: A[m=lane&15][k=quad*8+j], fp32->bf16 inline. [qt][khalf]
    short8 afr[2][2];
    #pragma unroll
    for (int qt = 0; qt < 2; ++qt)
        #pragma unroll
        for (int kh = 0; kh < 2; ++kh) {
            const float* qp = Qg + (size_t)(qBase + qt * 16 + m) * DDIM + quad * 8 + kh * 32;
            const float4 f0 = ((const float4*)qp)[0];
            const float4 f1 = ((const float4*)qp)[1];
            short8 a;
            a[0] = (short)bf16rne(f0.x); a[1] = (short)bf16rne(f0.y);
            a[2] = (short)bf16rne(f0.z); a[3] = (short)bf16rne(f0.w);
            a[4] = (short)bf16rne(f1.x); a[5] = (short)bf16rne(f1.y);
            a[6] = (short)bf16rne(f1.z); a[7] = (short)bf16rne(f1.w);
            afr[qt][kh] = a;
        }
    const f32x4 bias = {BIAS, BIAS, BIAS, BIAS};

    // 8 lists (query class = qt*4+reg), sorted top-2 pairs; row class = m
    uint32_t tA[8], tB[8];   // tA >= tB
    #pragma unroll
    for (int li = 0; li < 8; ++li) { tA[li] = 0u; tB[li] = 0u; }

    // staging: thread t owns 16B-slots t and t+512 of the 1024-slot subtile.
    // LDS slot (row=s>>3, c=s&7) holds global 16B-chunk (c ^ (row&7)) of that
    // row (same swizzle as before => compute reads unchanged, 2-way max).
    const int sr0 = t >> 3,          sc0 = (t & 7) ^ (sr0 & 7);
    const int sr1 = (t + 512) >> 3,  sc1 = (t & 7) ^ (sr1 & 7);   // (t+512)&7==t&7
    auto ld = [&](int sb, float4& a0, float4& a1, float4& b0, float4& b1) {
        const float* base = Mf + (size_t)(rowChunk + sb * SUB) * DDIM;
        const float4* p0 = (const float4*)(base + sr0 * DDIM + sc0 * 8);
        const float4* p1p = (const float4*)(base + sr1 * DDIM + sc1 * 8);
        a0 = p0[0]; a1 = p0[1];
        b0 = p1p[0]; b1 = p1p[1];
    };
    auto st = [&](int buf, float4 a0, float4 a1, float4 b0, float4 b1) {
        uint16_t* bp = stage + buf * 8192;
        uint4 w0, w1;
        w0.x = pack2(a0.x, a0.y); w0.y = pack2(a0.z, a0.w);
        w0.z = pack2(a1.x, a1.y); w0.w = pack2(a1.z, a1.w);
        w1.x = pack2(b0.x, b0.y); w1.y = pack2(b0.z, b0.w);
        w1.z = pack2(b1.x, b1.y); w1.w = pack2(b1.z, b1.w);
        *(uint4*)(bp + (size_t)t * 8) = w0;
        *(uint4*)(bp + (size_t)(t + 512) * 8) = w1;
    };

    float4 a0, a1, b0, b1;
    ld(0, a0, a1, b0, b1);
    st(0, a0, a1, b0, b1);
    #pragma unroll 2
    for (int sb = 0; sb < NSUB; ++sb) {
        if (sb + 1 < NSUB) ld(sb + 1, a0, a1, b0, b1);   // prefetch next subtile
        __syncthreads();                                 // buf[sb&1] visible
        const uint16_t* bufp = stage + (sb & 1) * 8192;
        const uint32_t pb = (uint32_t)m + (uint32_t)sb * 128u;   // row10 base
        #pragma unroll
        for (int rt = 0; rt < 8; ++rt) {
            const int r = rt * 16 + m;   // lane's row-in-subtile (B col n)
            const short8 v0 = *(const short8*)(bufp + r * 64 + ((quad       ^ (m & 7)) * 8));
            const short8 v1 = *(const short8*)(bufp + r * 64 + (((quad + 4) ^ (m & 7)) * 8));
            f32x4 c0, c1;
            c0 = __builtin_amdgcn_mfma_f32_16x16x32_bf16(afr[0][0], v0, bias, 0, 0, 0);
            c0 = __builtin_amdgcn_mfma_f32_16x16x32_bf16(afr[0][1], v1, c0,   0, 0, 0);
            c1 = __builtin_amdgcn_mfma_f32_16x16x32_bf16(afr[1][0], v0, bias, 0, 0, 0);
            c1 = __builtin_amdgcn_mfma_f32_16x16x32_bf16(afr[1][1], v1, c1,   0, 0, 0);
            const uint32_t posm = pb + (uint32_t)(rt * 16);   // (pos<<4)|m, <1024
            #pragma unroll
            for (int reg = 0; reg < 4; ++reg) {
                fold2(tA[reg],     tB[reg],     (__float_as_uint(c0[reg]) & SIMMASK) | posm);
                fold2(tA[4 + reg], tB[4 + reg], (__float_as_uint(c1[reg]) & SIMMASK) | posm);
            }
        }
        if (sb + 1 < NSUB) st((sb + 1) & 1, a0, a1, b0, b1);  // other buffer: safe
    }

    // merge 16 row-classes per query: butterfly xor 1,2,4,8 across m lanes.
    // Two qtile groups sequentially (16 regs peak). Keys carry row10.
    #pragma unroll
    for (int g = 0; g < 2; ++g) {
        uint32_t fl[4][4];
        #pragma unroll
        for (int r4 = 0; r4 < 4; ++r4) {
            fl[r4][0] = tA[g * 4 + r4]; fl[r4][1] = tB[g * 4 + r4];
            fl[r4][2] = 0u;             fl[r4][3] = 0u;
        }
        #pragma unroll
        for (int d = 1; d <= 8; d <<= 1) {
            const int nv = (d == 1) ? 2 : 4;   // remote valid count
            #pragma unroll
            for (int r4 = 0; r4 < 4; ++r4) {
                uint32_t rm[4];
                #pragma unroll
                for (int s = 0; s < 4; ++s)
                    if (s < nv) rm[s] = __shfl_xor(fl[r4][s], d, 64);
                #pragma unroll
                for (int s = 0; s < 4; ++s)
                    if (s < nv) fold4(fl[r4], rm[s]);
            }
        }
        if (m == 0) {   // lanes 0,16,32,48 hold merged lists for this group
            #pragma unroll
            for (int r4 = 0; r4 < 4; ++r4) {
                const int q = qBase + g * 16 + quad * 4 + r4;
                uint4 v4; v4.x = fl[r4][0]; v4.y = fl[r4][1];
                v4.z = fl[r4][2]; v4.w = fl[r4][3];
                *(uint4*)(wsK + ((size_t)chunk * NQ + (size_t)q) * KC_PER) = v4;
            }
        }
    }
}

// Kernel 2: 4 query-waves per 256-thr block. 256 chunks x 4 keys (uint4
// loads) -> top-16 by prefilter sim -> parallel row loads -> exact fp32
// rescore -> top-5 -> gather.
__global__ __launch_bounds__(256) void p2(const float* __restrict__ Qg,
                                          const float* __restrict__ Mf,
                                          const uint32_t* __restrict__ wsK,
                                          float* __restrict__ out) {
    const int Q = blockIdx.x * 4 + (threadIdx.x >> 6);
    const int lane = threadIdx.x & 63;
    u64 mk[16];
    #pragma unroll
    for (int i = 0; i < 4; ++i) {
        const int c = i * 64 + lane;             // chunk id
        const uint4 k4 = *(const uint4*)(wsK + ((size_t)c * NQ + (size_t)Q) * KC_PER);
        const uint32_t cb = (uint32_t)c * (uint32_t)CHUNK;
        mk[i * 4 + 0] = ((u64)k4.x << 32) | (u64)(cb + (k4.x & 1023u));
        mk[i * 4 + 1] = ((u64)k4.y << 32) | (u64)(cb + (k4.y & 1023u));
        mk[i * 4 + 2] = ((u64)k4.z << 32) | (u64)(cb + (k4.z & 1023u));
        mk[i * 4 + 3] = ((u64)k4.w << 32) | (u64)(cb + (k4.w & 1023u));
    }
    uint32_t idxs[16];
    #pragma unroll
    for (int it = 0; it < 16; ++it) {
        u64 wk = mk[0];
        #pragma unroll
        for (int i2 = 1; i2 < 16; ++i2) wk = mk[i2] > wk ? mk[i2] : wk;
        #pragma unroll
        for (int off = 32; off >= 1; off >>= 1) {
            const u64 o = __shfl_xor(wk, off, 64);
            wk = o > wk ? o : wk;
        }
        #pragma unroll
        for (int i2 = 0; i2 < 16; ++i2) if (mk[i2] == wk) mk[i2] = 0;  // unique
        idxs[it] = (uint32_t)wk & (KROWS - 1u);  // global row, wave-uniform
    }
    // 16 independent row loads (latency overlapped), exact fp32 rescore
    const float qv = Qg[(size_t)Q * DDIM + lane];
    float v[16];
    #pragma unroll
    for (int j = 0; j < 16; ++j) v[j] = Mf[(size_t)idxs[j] * DDIM + lane];
    u64 rk[16];
    #pragma unroll
    for (int j = 0; j < 16; ++j) {
        float p = qv * v[j];
        #pragma unroll
        for (int off = 32; off >= 1; off >>= 1) p += __shfl_xor(p, off, 64);
        rk[j] = ((u64)ord32(p) << 32) | (u64)(~idxs[j]);   // ties -> lower idx
    }
    #pragma unroll
    for (int it = 0; it < 5; ++it) {
        u64 best = rk[0];
        #pragma unroll
        for (int j = 1; j < 16; ++j) best = rk[j] > best ? rk[j] : best;
        float o = 0.f;
        #pragma unroll
        for (int j = 0; j < 16; ++j) o = (rk[j] == best) ? v[j] : o;  // unique
        out[((size_t)Q * 5 + it) * DDIM + lane] = o;
        #pragma unroll
        for (int j = 0; j < 16; ++j) rk[j] = (rk[j] == best) ? 0ull : rk[j];
    }
}

extern "C" void kernel_launch(void* const* d_in, const int* in_sizes, int n_in,
                              void* d_out, int out_size, void* d_ws, size_t ws_size,
                              hipStream_t stream) {
    const float* Qg = (const float*)d_in[0];
    const float* Mf = (const float*)d_in[1];
    float* out = (float*)d_out;
    uint32_t* wsK = (uint32_t*)d_ws;   // 256*1024*4*4 = 4 MB

    p1<<<dim3(4, NC), 512, 0, stream>>>(Qg, Mf, wsK);
    p2<<<NQ / 4, 256, 0, stream>>>(Qg, Mf, wsK, out);
}

// Round 8
// 175.525 us; speedup vs baseline: 2.0632x; 2.0632x over previous
//
#include <hip/hip_runtime.h>
#include <stdint.h>

typedef unsigned long long u64;
typedef __attribute__((ext_vector_type(8))) short short8;   // 8 bf16 (4 VGPRs)
typedef __attribute__((ext_vector_type(4))) float f32x4;

#define KROWS  262144
#define DDIM   64
#define NQ     1024
#define NC     256                // K-chunks
#define CHUNK  (KROWS / NC)       // 1024 rows
#define SUB    128                // rows per LDS subtile
#define NSUB   (CHUNK / SUB)      // 8
#define KC_PER 4                  // u32 keys kept per (chunk,query) = one uint4
#define BIAS   128.0f             // acc bias => sims positive => raw bits monotone
#define SIMMASK 0xFFFFFC00u       // top 22 bits sim, low 10 bits row-in-chunk

__device__ __forceinline__ uint32_t ord32(float f) {
    uint32_t u = __float_as_uint(f);
    return (u & 0x80000000u) ? ~u : (u | 0x80000000u);
}
__device__ __forceinline__ uint32_t maxu(uint32_t a, uint32_t b) { return a > b ? a : b; }
__device__ __forceinline__ uint32_t minu(uint32_t a, uint32_t b) { return a < b ? a : b; }
// sorted-desc pair fold: 3 VALU
__device__ __forceinline__ void fold2(uint32_t& t0, uint32_t& t1, uint32_t k) {
    t1 = maxu(t1, minu(t0, k));
    t0 = maxu(t0, k);
}
// sorted-desc 4-list fold: 7 VALU
__device__ __forceinline__ void fold4(uint32_t (&t)[4], uint32_t k) {
    uint32_t n1 = maxu(t[1], minu(t[0], k));
    uint32_t n2 = maxu(t[2], minu(t[1], k));
    uint32_t n3 = maxu(t[3], minu(t[2], k));
    t[0] = maxu(t[0], k);
    t[1] = n1; t[2] = n2; t[3] = n3;
}
__device__ __forceinline__ uint32_t bf16rne(float f) {
    uint32_t u = __float_as_uint(f);
    return (u + 0x7fffu + ((u >> 16) & 1u)) >> 16;
}
__device__ __forceinline__ uint32_t pack2(float a, float b) {
    return bf16rne(a) | (bf16rne(b) << 16);
}

// Kernel 1: bf16 MFMA prefilter with FUSED fp32->bf16 staging (no conv
// kernel). Anti-spill design (R5/R7 post-mortems): (a) prefetch live range
// is ~10 instrs — ld(sb+1) and st(sb+1) are adjacent, both before compute(sb),
// so the float4s die at the pack2s; (b) amdgpu_waves_per_eu(4,6) gives the
// allocator a legal 85-reg budget so it cannot spill chasing the 64-reg tier.
__global__ __launch_bounds__(512)
__attribute__((amdgpu_waves_per_eu(4, 6)))
void p1(const float* __restrict__ Qg,
        const float* __restrict__ Mf,
        uint32_t* __restrict__ wsK) {
    __shared__ __align__(16) uint16_t stage[2 * 8192];   // 2 x 16 KiB dbuf
    const int t = threadIdx.x;
    const int lane = t & 63;
    const int w = t >> 6;
    const int quad = lane >> 4;
    const int m = lane & 15;
    const int qcol = blockIdx.x;
    const int chunk = blockIdx.y;
    const int qBase = qcol * 256 + w * 32;
    const int rowChunk = chunk * CHUNK;

    // A-frags: A[m=lane&15][k=quad*8+j], fp32->bf16 inline. [qt][khalf]
    short8 afr[2][2];
    #pragma unroll
    for (int qt = 0; qt < 2; ++qt)
        #pragma unroll
        for (int kh = 0; kh < 2; ++kh) {
            const float* qp = Qg + (size_t)(qBase + qt * 16 + m) * DDIM + quad * 8 + kh * 32;
            const float4 f0 = ((const float4*)qp)[0];
            const float4 f1 = ((const float4*)qp)[1];
            short8 a;
            a[0] = (short)bf16rne(f0.x); a[1] = (short)bf16rne(f0.y);
            a[2] = (short)bf16rne(f0.z); a[3] = (short)bf16rne(f0.w);
            a[4] = (short)bf16rne(f1.x); a[5] = (short)bf16rne(f1.y);
            a[6] = (short)bf16rne(f1.z); a[7] = (short)bf16rne(f1.w);
            afr[qt][kh] = a;
        }
    const f32x4 bias = {BIAS, BIAS, BIAS, BIAS};

    // 8 lists (query class = qt*4+reg), sorted top-2 pairs; row class = m
    uint32_t tA[8], tB[8];   // tA >= tB
    #pragma unroll
    for (int li = 0; li < 8; ++li) { tA[li] = 0u; tB[li] = 0u; }

    // staging: thread t owns 16B-slots t and t+512 of the 1024-slot subtile.
    // LDS slot (row=s>>3, c=s&7) holds global 16B-chunk (c ^ (row&7)) of that
    // row (same swizzle as R6 => compute reads unchanged, 2-way max).
    const int sr0 = t >> 3;
    const int sc0 = (t & 7) ^ (sr0 & 7);   // note (t+512)>>3 has same &7 => same sc
    // load + convert + store back-to-back: float4s die immediately (no
    // cross-compute live range — R7's spill cause)
    auto stage_sub = [&](int sb, int buf) {
        const float* base = Mf + (size_t)(rowChunk + sb * SUB) * DDIM + sr0 * DDIM + sc0 * 8;
        const float4 a0 = ((const float4*)base)[0];
        const float4 a1 = ((const float4*)base)[1];
        const float4 b0 = ((const float4*)(base + 64 * DDIM))[0];
        const float4 b1 = ((const float4*)(base + 64 * DDIM))[1];
        uint16_t* bp = stage + buf * 8192;
        uint4 w0, w1;
        w0.x = pack2(a0.x, a0.y); w0.y = pack2(a0.z, a0.w);
        w0.z = pack2(a1.x, a1.y); w0.w = pack2(a1.z, a1.w);
        w1.x = pack2(b0.x, b0.y); w1.y = pack2(b0.z, b0.w);
        w1.z = pack2(b1.x, b1.y); w1.w = pack2(b1.z, b1.w);
        *(uint4*)(bp + (size_t)t * 8) = w0;
        *(uint4*)(bp + (size_t)(t + 512) * 8) = w1;
    };

    stage_sub(0, 0);
    #pragma unroll 2
    for (int sb = 0; sb < NSUB; ++sb) {
        __syncthreads();   // staging of sb (prev iter) visible to all waves
        if (sb + 1 < NSUB) stage_sub(sb + 1, (sb + 1) & 1);  // other buffer: safe
        const uint16_t* bufp = stage + (sb & 1) * 8192;
        const uint32_t pb = (uint32_t)m + (uint32_t)sb * 128u;   // row10 base
        #pragma unroll
        for (int rt = 0; rt < 8; ++rt) {
            const int r = rt * 16 + m;   // lane's row-in-subtile (B col n)
            const short8 v0 = *(const short8*)(bufp + r * 64 + ((quad       ^ (m & 7)) * 8));
            const short8 v1 = *(const short8*)(bufp + r * 64 + (((quad + 4) ^ (m & 7)) * 8));
            f32x4 c0, c1;
            c0 = __builtin_amdgcn_mfma_f32_16x16x32_bf16(afr[0][0], v0, bias, 0, 0, 0);
            c0 = __builtin_amdgcn_mfma_f32_16x16x32_bf16(afr[0][1], v1, c0,   0, 0, 0);
            c1 = __builtin_amdgcn_mfma_f32_16x16x32_bf16(afr[1][0], v0, bias, 0, 0, 0);
            c1 = __builtin_amdgcn_mfma_f32_16x16x32_bf16(afr[1][1], v1, c1,   0, 0, 0);
            const uint32_t posm = pb + (uint32_t)(rt * 16);   // (pos<<4)|m, <1024
            #pragma unroll
            for (int reg = 0; reg < 4; ++reg) {
                fold2(tA[reg],     tB[reg],     (__float_as_uint(c0[reg]) & SIMMASK) | posm);
                fold2(tA[4 + reg], tB[4 + reg], (__float_as_uint(c1[reg]) & SIMMASK) | posm);
            }
        }
    }

    // merge 16 row-classes per query: butterfly xor 1,2,4,8 across m lanes.
    // Two qtile groups sequentially (16 regs peak). Keys carry row10.
    #pragma unroll
    for (int g = 0; g < 2; ++g) {
        uint32_t fl[4][4];
        #pragma unroll
        for (int r4 = 0; r4 < 4; ++r4) {
            fl[r4][0] = tA[g * 4 + r4]; fl[r4][1] = tB[g * 4 + r4];
            fl[r4][2] = 0u;             fl[r4][3] = 0u;
        }
        #pragma unroll
        for (int d = 1; d <= 8; d <<= 1) {
            const int nv = (d == 1) ? 2 : 4;   // remote valid count
            #pragma unroll
            for (int r4 = 0; r4 < 4; ++r4) {
                uint32_t rm[4];
                #pragma unroll
                for (int s = 0; s < 4; ++s)
                    if (s < nv) rm[s] = __shfl_xor(fl[r4][s], d, 64);
                #pragma unroll
                for (int s = 0; s < 4; ++s)
                    if (s < nv) fold4(fl[r4], rm[s]);
            }
        }
        if (m == 0) {   // lanes 0,16,32,48 hold merged lists for this group
            #pragma unroll
            for (int r4 = 0; r4 < 4; ++r4) {
                const int q = qBase + g * 16 + quad * 4 + r4;
                uint4 v4; v4.x = fl[r4][0]; v4.y = fl[r4][1];
                v4.z = fl[r4][2]; v4.w = fl[r4][3];
                *(uint4*)(wsK + ((size_t)chunk * NQ + (size_t)q) * KC_PER) = v4;
            }
        }
    }
}

// Kernel 2: 4 query-waves per 256-thr block. 256 chunks x 4 keys (uint4
// loads) -> top-16 by prefilter sim -> parallel row loads -> exact fp32
// rescore -> top-5 -> gather.
__global__ __launch_bounds__(256) void p2(const float* __restrict__ Qg,
                                          const float* __restrict__ Mf,
                                          const uint32_t* __restrict__ wsK,
                                          float* __restrict__ out) {
    const int Q = blockIdx.x * 4 + (threadIdx.x >> 6);
    const int lane = threadIdx.x & 63;
    u64 mk[16];
    #pragma unroll
    for (int i = 0; i < 4; ++i) {
        const int c = i * 64 + lane;             // chunk id
        const uint4 k4 = *(const uint4*)(wsK + ((size_t)c * NQ + (size_t)Q) * KC_PER);
        const uint32_t cb = (uint32_t)c * (uint32_t)CHUNK;
        mk[i * 4 + 0] = ((u64)k4.x << 32) | (u64)(cb + (k4.x & 1023u));
        mk[i * 4 + 1] = ((u64)k4.y << 32) | (u64)(cb + (k4.y & 1023u));
        mk[i * 4 + 2] = ((u64)k4.z << 32) | (u64)(cb + (k4.z & 1023u));
        mk[i * 4 + 3] = ((u64)k4.w << 32) | (u64)(cb + (k4.w & 1023u));
    }
    uint32_t idxs[16];
    #pragma unroll
    for (int it = 0; it < 16; ++it) {
        u64 wk = mk[0];
        #pragma unroll
        for (int i2 = 1; i2 < 16; ++i2) wk = mk[i2] > wk ? mk[i2] : wk;
        #pragma unroll
        for (int off = 32; off >= 1; off >>= 1) {
            const u64 o = __shfl_xor(wk, off, 64);
            wk = o > wk ? o : wk;
        }
        #pragma unroll
        for (int i2 = 0; i2 < 16; ++i2) if (mk[i2] == wk) mk[i2] = 0;  // unique
        idxs[it] = (uint32_t)wk & (KROWS - 1u);  // global row, wave-uniform
    }
    // 16 independent row loads (latency overlapped), exact fp32 rescore
    const float qv = Qg[(size_t)Q * DDIM + lane];
    float v[16];
    #pragma unroll
    for (int j = 0; j < 16; ++j) v[j] = Mf[(size_t)idxs[j] * DDIM + lane];
    u64 rk[16];
    #pragma unroll
    for (int j = 0; j < 16; ++j) {
        float p = qv * v[j];
        #pragma unroll
        for (int off = 32; off >= 1; off >>= 1) p += __shfl_xor(p, off, 64);
        rk[j] = ((u64)ord32(p) << 32) | (u64)(~idxs[j]);   // ties -> lower idx
    }
    #pragma unroll
    for (int it = 0; it < 5; ++it) {
        u64 best = rk[0];
        #pragma unroll
        for (int j = 1; j < 16; ++j) best = rk[j] > best ? rk[j] : best;
        float o = 0.f;
        #pragma unroll
        for (int j = 0; j < 16; ++j) o = (rk[j] == best) ? v[j] : o;  // unique
        out[((size_t)Q * 5 + it) * DDIM + lane] = o;
        #pragma unroll
        for (int j = 0; j < 16; ++j) rk[j] = (rk[j] == best) ? 0ull : rk[j];
    }
}

extern "C" void kernel_launch(void* const* d_in, const int* in_sizes, int n_in,
                              void* d_out, int out_size, void* d_ws, size_t ws_size,
                              hipStream_t stream) {
    const float* Qg = (const float*)d_in[0];
    const float* Mf = (const float*)d_in[1];
    float* out = (float*)d_out;
    uint32_t* wsK = (uint32_t*)d_ws;   // 256*1024*4*4 = 4 MB

    p1<<<dim3(4, NC), 512, 0, stream>>>(Qg, Mf, wsK);
    p2<<<NQ / 4, 256, 0, stream>>>(Qg, Mf, wsK, out);
}